// Round 2
// baseline (144.966 us; speedup 1.0000x reference)
//
#include <hip/hip_runtime.h>

#ifndef __has_builtin
#define __has_builtin(x) 0
#endif

#if __has_builtin(__builtin_amdgcn_exp2f)
#define EXP2F(x) __builtin_amdgcn_exp2f(x)
#else
#define EXP2F(x) exp2f(x)
#endif

#if __has_builtin(__builtin_amdgcn_rcpf)
#define RCPF(x) __builtin_amdgcn_rcpf(x)
#else
#define RCPF(x) (1.0f / (x))
#endif

#define LOG2E_F 1.4426950408889634f

// nck exp-arg constants, exp(a) = exp2(a*log2e) folded:
//   f_na: exp(6.39 - z/8.98)      -> exp2(z*CA1 + CA0)
//   f_ca: exp(-4.4 - z/4.25)      -> exp2(z*CB1 + CB0)
//   f_k : exp(-0.132*(z - 16.74)) -> exp2(z*CC1 + CC0)
#define CA1 (-0.16065646437f)
#define CA0 ( 9.2188213109f)
#define CB1 (-0.33945766845f)
#define CB0 (-6.3478581799f)
#define CC1 (-0.19043574540f)
#define CC0 ( 3.1878943779f)

struct TreeParams {
  const float* w[9];
  const float* b[9];
};

__device__ __forceinline__ float nck_eval(float z, float A1, float A0,
                                          float B1, float B0, float G) {
  float ea = EXP2F(fmaf(z, CA1, CA0));
  float eb = EXP2F(fmaf(z, CB1, CB0));
  float ec = EXP2F(fmaf(z, CC1, CC0));
  float ra = RCPF(1.0f + ea);
  float rb = RCPF(1.0f + eb);
  float rc = RCPF(0.436f + ec);
  return fmaf(fmaf(z, A1, A0), ra, fmaf(fmaf(z, B1, B0), rb, G * rc));
}

// Ground-truth wiring (hand-traced from _build_levels; DEPTH=2 miniature
// fully simulated to confirm):
//   V_8[k]  = nck(x[:,255-k]*w0[k] + b0[255+k])
//   V_d[q]  = nck(w_{8-d}[2q]  * V_{d+1}[~(2q)]        (~ = complement in d+1 bits)
//           +     w_{8-d}[2q+1]* V_{d+1}[~(2q+1)] + b_{8-d}[2^d-1+q])
//   out     = sigmoid(root_w * V_0[0] + root_b)
// DFS by branch bits ig = a1..a8 (a=0 child first):
//   index at depth d: q_d = (ig >> (8-d)) ^ (0x55 & ((1<<d)-1))
//   leaf: weight w0[ig^0x55], x col = ig^0xAA, bias b0[255 + (ig^0x55)]
//   merge at parent depth d: k = q_d, concat-w offset 768 - 2^(d+2),
//     z = w[2k]*(first child) + w[2k+1]*(second child) + bc[2^d-1+k]
// Mapping: wave j = tid>>6 owns DFS prefix j (subtree root depth 2,
// q2 = j^1); lane e = tid&63 owns element e. All tree indices wave-uniform.

__global__ __launch_bounds__(256, 2)
void asym_tree_fwd(const float* __restrict__ x, TreeParams p,
                   const float* __restrict__ alpha_p,
                   const float* __restrict__ beta_p,
                   const float* __restrict__ gamma_p,
                   const float* __restrict__ rw_p,
                   const float* __restrict__ rb_p,
                   float* __restrict__ out) {
  __shared__ float xs[64 * 257];  // stride 257: read banks (e+col)%32 -> 2-way
  __shared__ float wc[766];       // concat w0..w8 @ 0,256,512,640,704,736,752,760,764
  __shared__ float bc[511];       // bias per node id
  __shared__ float stk[7 * 256];  // DFS stack, slot = depth-2; bank tid%32 -> 2-way
  __shared__ float v2[4][64];     // depth-2 subtree results for top combine

  const int tid = threadIdx.x;

  // ---- stage weights + biases ----
  {
    const int wsz[9] = {256, 256, 128, 64, 32, 16, 8, 4, 2};
    int off = 0;
#pragma unroll
    for (int l = 0; l < 9; ++l) {
      if (tid < wsz[l]) wc[off + tid] = p.w[l][tid];
      off += wsz[l];
    }
#pragma unroll
    for (int l = 0; l < 9; ++l) {
      int d = 8 - l;
      int base = (1 << d) - 1;
      int cnt = 1 << d;
      for (int i = tid; i < cnt; i += 256) bc[base + i] = p.b[l][base + i];
    }
  }

  // ---- stage x: 64 rows x 256 cols, coalesced float4 global reads ----
  {
    const float4* src =
        reinterpret_cast<const float4*>(x + (size_t)blockIdx.x * 64 * 256);
#pragma unroll
    for (int it = 0; it < 16; ++it) {
      int f4 = it * 256 + tid;      // 0..4095
      float4 v = src[f4];
      int e = f4 >> 6;              // row 0..63
      int c = (f4 & 63) << 2;       // col 0..252
      float* dst = &xs[e * 257 + c];
      dst[0] = v.x; dst[1] = v.y; dst[2] = v.z; dst[3] = v.w;
    }
  }
  __syncthreads();

  const float alpha = alpha_p[0], beta = beta_p[0], gamma = gamma_p[0];
  const float A1 = alpha * 0.0878f, A0 = -A1 * 113.68f;
  const float B1 = beta * 0.129f,   B0 = -B1 * 69.62f;
  const float G  = gamma * 2.23f;

  const int e = tid & 63;   // element (lane)
  const int j = tid >> 6;   // subtree (wave) -> all tree indices wave-uniform
  const float* xrow = &xs[e * 257];

  float v = 0.0f;
#pragma unroll 4
  for (int t = 0; t < 64; ++t) {
    const int ig = (j << 6) | t;          // DFS leaf position
    const int k8 = ig ^ 0x55;             // leaf weight/bias index
    const int col = ig ^ 0xAA;            // x column (wave-uniform)
    v = nck_eval(fmaf(xrow[col], wc[k8], bc[255 + k8]), A1, A0, B1, B0, G);

    int dv = 8;
    int tt = t;
    while (tt & 1) {                      // t block-uniform: no divergence
      const float vl = stk[(dv - 2) * 256 + tid];  // first-visited sibling
      dv -= 1;                                     // parent depth
      const int kd = (ig >> (8 - dv)) ^ (0x55 & ((1 << dv) - 1));
      const int wo = 768 - (1 << (dv + 2));
      const float z = fmaf(wc[wo + 2 * kd], vl,          // w[2k] * first child
                           fmaf(wc[wo + 2 * kd + 1], v,  // w[2k+1] * second
                                bc[(1 << dv) - 1 + kd]));
      v = nck_eval(z, A1, A0, B1, B0, G);
      tt >>= 1;
    }
    stk[(dv - 2) * 256 + tid] = v;
  }
  // v = V_2[j^1] for element e
  v2[j][e] = v;
  __syncthreads();

  // ---- top 2 levels + sigmoid, wave 0 only ----
  if (tid < 64) {
    // V_1[1] (a1=0): children q2=1 (wave0), q2=0 (wave1); w7 = wc[760..764)
    const float vA = nck_eval(
        fmaf(wc[762], v2[0][tid], fmaf(wc[763], v2[1][tid], bc[2])),
        A1, A0, B1, B0, G);
    // V_1[0] (a1=1): children q2=3 (wave2), q2=2 (wave3)
    const float vB = nck_eval(
        fmaf(wc[760], v2[2][tid], fmaf(wc[761], v2[3][tid], bc[1])),
        A1, A0, B1, B0, G);
    // root: w8[0]*V_1[1] + w8[1]*V_1[0] + b8[0]
    const float y = nck_eval(fmaf(wc[764], vA, fmaf(wc[765], vB, bc[0])),
                             A1, A0, B1, B0, G);
    const float o = fmaf(rw_p[0], y, rb_p[0]);
    out[(size_t)blockIdx.x * 64 + tid] =
        RCPF(1.0f + EXP2F(-o * LOG2E_F));  // sigmoid
  }
}

extern "C" void kernel_launch(void* const* d_in, const int* in_sizes, int n_in,
                              void* d_out, int out_size, void* d_ws,
                              size_t ws_size, hipStream_t stream) {
  (void)n_in; (void)d_ws; (void)ws_size; (void)out_size;
  // setup_inputs order: x, w0,b0, w1,b1, ..., w8,b8, alpha, beta, gamma,
  // root_w, root_b
  const float* x = (const float*)d_in[0];
  TreeParams p;
  for (int l = 0; l < 9; ++l) {
    p.w[l] = (const float*)d_in[1 + 2 * l];
    p.b[l] = (const float*)d_in[2 + 2 * l];
  }
  const float* alpha = (const float*)d_in[19];
  const float* beta  = (const float*)d_in[20];
  const float* gamma = (const float*)d_in[21];
  const float* rw    = (const float*)d_in[22];
  const float* rb    = (const float*)d_in[23];
  float* out = (float*)d_out;

  const int batch = in_sizes[0] / 256;   // 32768
  const int grid = batch / 64;           // 512 blocks x 256 threads
  asym_tree_fwd<<<grid, 256, 0, stream>>>(x, p, alpha, beta, gamma, rw, rb, out);
}

// Round 3
// 138.843 us; speedup vs baseline: 1.0441x; 1.0441x over previous
//
#include <hip/hip_runtime.h>

#ifndef __has_builtin
#define __has_builtin(x) 0
#endif

#if __has_builtin(__builtin_amdgcn_exp2f)
#define EXP2F(x) __builtin_amdgcn_exp2f(x)
#else
#define EXP2F(x) exp2f(x)
#endif

#if __has_builtin(__builtin_amdgcn_rcpf)
#define RCPF(x) __builtin_amdgcn_rcpf(x)
#else
#define RCPF(x) (1.0f / (x))
#endif

#define LOG2E_F 1.4426950408889634f

// nck exp-arg constants, exp(a) = exp2(a*log2e) folded (bit-exact vs ref, R2):
#define CA1 (-0.16065646437f)
#define CA0 ( 9.2188213109f)
#define CB1 (-0.33945766845f)
#define CB0 (-6.3478581799f)
#define CC1 (-0.19043574540f)
#define CC0 ( 3.1878943779f)

struct TreeParams {
  const float* w[9];
  const float* b[9];
};

__device__ __forceinline__ float nck_eval(float z, float A1, float A0,
                                          float B1, float B0, float G) {
  float ea = EXP2F(fmaf(z, CA1, CA0));
  float eb = EXP2F(fmaf(z, CB1, CB0));
  float ec = EXP2F(fmaf(z, CC1, CC0));
  float ra = RCPF(1.0f + ea);
  float rb = RCPF(1.0f + eb);
  float rc = RCPF(0.436f + ec);
  return fmaf(fmaf(z, A1, A0), ra, fmaf(fmaf(z, B1, B0), rb, G * rc));
}

// Wiring (verified bit-exact in R2):
//   V_8[k] = nck(x[:,255-k]*w0[k] + b0[255+k])
//   merge at parent depth d, node index k = pre_d ^ (0x55 & ((1<<d)-1)):
//     z = w[2k]*(first DFS child) + w[2k+1]*(second) + bc[2^d-1+k],
//     concat-w offset wo(d) = 768 - 2^(d+2)
//   leaf at DFS pos ig: k8 = ig^0x55, x col = ig^0xAA
// New mapping: block = 512 thr = 8 waves; wave w = DFS prefix (depth-3
// subtree, pre3 = w), lane e = element. All tree indices wave-uniform;
// x (32 floats/lane) and the DFS stack live in REGISTERS via full
// compile-time unroll (recursive template, all indices constexpr).

template <int I>
__device__ __forceinline__ float xget(const float4* xr) {
  constexpr int q = I >> 2, r = I & 3;
  if constexpr (r == 0) return xr[q].x;
  else if constexpr (r == 1) return xr[q].y;
  else if constexpr (r == 2) return xr[q].z;
  else return xr[q].w;
}

struct Ctx {
  const float4* xr;   // 8 float4 = lane's 32 x values (cols cb..cb+31)
  const float* wc;    // LDS concat weights (766)
  const float* bc;    // LDS biases by node id (511)
  int w;              // wave id 0..7 (= pre3)
  float A1, A0, B1, B0, G;
};

template <int D, int CPRE>
__device__ __forceinline__ float node_eval(const Ctx& c) {
  if constexpr (D == 8) {
    constexpr int t = CPRE;                        // local leaf 0..31
    const int k8 = ((c.w ^ 2) << 5) | (t ^ 0x15);  // = ((w<<5)|t) ^ 0x55
    const float xv = xget<(t ^ 0x0A)>(c.xr);       // col = ig^0xAA, low 5 bits
    return nck_eval(fmaf(xv, c.wc[k8], c.bc[255 + k8]),
                    c.A1, c.A0, c.B1, c.B0, c.G);
  } else {
    const float a = node_eval<D + 1, 2 * CPRE>(c);      // first DFS child
    const float b = node_eval<D + 1, 2 * CPRE + 1>(c);  // second
    const int k = ((c.w << (D - 3)) | CPRE) ^ (0x55 & ((1 << D) - 1));
    constexpr int wo = 768 - (1 << (D + 2));
    const float z = fmaf(c.wc[wo + 2 * k], a,
                         fmaf(c.wc[wo + 2 * k + 1], b,
                              c.bc[(1 << D) - 1 + k]));
    return nck_eval(z, c.A1, c.A0, c.B1, c.B0, c.G);
  }
}

__global__ __launch_bounds__(512, 4)
void asym_tree_fwd(const float* __restrict__ x, TreeParams p,
                   const float* __restrict__ alpha_p,
                   const float* __restrict__ beta_p,
                   const float* __restrict__ gamma_p,
                   const float* __restrict__ rw_p,
                   const float* __restrict__ rb_p,
                   float* __restrict__ out) {
  __shared__ float wc[766];      // w0..w8 @ 0,256,512,640,704,736,752,760,764
  __shared__ float bc[511];      // bias per node id
  __shared__ float v3[8][64];    // depth-3 results; reads: uniform row -> 2-way

  const int tid = threadIdx.x;
  const int e = tid & 63;        // element (lane)
  const int w = tid >> 6;        // wave = depth-3 DFS prefix

  // ---- issue x loads first (hide under param staging) ----
  // lane e needs cols [((w^5)<<5), +32) of row (block*64 + e); 64B lines are
  // fully consumed by 4 consecutive dwordx4 within the same wave -> 32MB HBM.
  const float4* xsrc = reinterpret_cast<const float4*>(
      x + (((size_t)blockIdx.x * 64 + e) * 256 + ((w ^ 5) << 5)));
  float4 xr[8];
#pragma unroll
  for (int i = 0; i < 8; ++i) xr[i] = xsrc[i];

  // ---- stage weights + biases to LDS (wave-uniform broadcast reads later) --
  {
    const int wsz[9] = {256, 256, 128, 64, 32, 16, 8, 4, 2};
    int off = 0;
#pragma unroll
    for (int l = 0; l < 9; ++l) {
      if (tid < wsz[l]) wc[off + tid] = p.w[l][tid];
      off += wsz[l];
    }
#pragma unroll
    for (int l = 0; l < 9; ++l) {
      int d = 8 - l;
      int base = (1 << d) - 1;
      int cnt = 1 << d;
      for (int i = tid; i < cnt; i += 512) bc[base + i] = p.b[l][base + i];
    }
  }
  __syncthreads();

  const float alpha = alpha_p[0], beta = beta_p[0], gamma = gamma_p[0];
  Ctx c;
  c.xr = xr; c.wc = wc; c.bc = bc; c.w = w;
  c.A1 = alpha * 0.0878f; c.A0 = -c.A1 * 113.68f;
  c.B1 = beta * 0.129f;   c.B0 = -c.B1 * 69.62f;
  c.G  = gamma * 2.23f;

  // ---- fully-unrolled register DFS: depth-3 subtree (32 leaves) ----
  v3[w][e] = node_eval<3, 0>(c);
  __syncthreads();

  // ---- top 3 levels + sigmoid on wave 0 ----
  if (w == 0) {
    float v2[4];
#pragma unroll
    for (int q = 0; q < 4; ++q) {   // depth-2 node pre2=q, k2=q^1, wo=752
      const int k2 = q ^ 1;
      v2[q] = nck_eval(fmaf(wc[752 + 2 * k2], v3[2 * q][e],
                            fmaf(wc[753 + 2 * k2], v3[2 * q + 1][e],
                                 bc[3 + k2])),
                       c.A1, c.A0, c.B1, c.B0, c.G);
    }
    float v1[2];
#pragma unroll
    for (int q = 0; q < 2; ++q) {   // depth-1 node pre1=q, k1=q^1, wo=760
      const int k1 = q ^ 1;
      v1[q] = nck_eval(fmaf(wc[760 + 2 * k1], v2[2 * q],
                            fmaf(wc[761 + 2 * k1], v2[2 * q + 1], bc[1 + k1])),
                       c.A1, c.A0, c.B1, c.B0, c.G);
    }
    // root: wo=764, k=0
    const float y = nck_eval(fmaf(wc[764], v1[0], fmaf(wc[765], v1[1], bc[0])),
                             c.A1, c.A0, c.B1, c.B0, c.G);
    const float o = fmaf(rw_p[0], y, rb_p[0]);
    out[(size_t)blockIdx.x * 64 + e] = RCPF(1.0f + EXP2F(-o * LOG2E_F));
  }
}

extern "C" void kernel_launch(void* const* d_in, const int* in_sizes, int n_in,
                              void* d_out, int out_size, void* d_ws,
                              size_t ws_size, hipStream_t stream) {
  (void)n_in; (void)d_ws; (void)ws_size; (void)out_size;
  const float* x = (const float*)d_in[0];
  TreeParams p;
  for (int l = 0; l < 9; ++l) {
    p.w[l] = (const float*)d_in[1 + 2 * l];
    p.b[l] = (const float*)d_in[2 + 2 * l];
  }
  const float* alpha = (const float*)d_in[19];
  const float* beta  = (const float*)d_in[20];
  const float* gamma = (const float*)d_in[21];
  const float* rw    = (const float*)d_in[22];
  const float* rb    = (const float*)d_in[23];
  float* out = (float*)d_out;

  const int batch = in_sizes[0] / 256;   // 32768
  const int grid = batch / 64;           // 512 blocks x 512 threads (8 waves)
  asym_tree_fwd<<<grid, 512, 0, stream>>>(x, p, alpha, beta, gamma, rw, rb,
                                          out);
}